// Round 18
// baseline (219.160 us; speedup 1.0000x reference)
//
#include <hip/hip_runtime.h>
#include <hip/hip_bf16.h>
#include <stdint.h>
#include <math.h>

#define NHEAD 16
#define DK 64
#define SEQ 2048
#define BATCH 2
#define DMODEL 1024

typedef __attribute__((ext_vector_type(8))) short short8_t;
typedef __attribute__((ext_vector_type(4))) short short4_t;
typedef __attribute__((ext_vector_type(4))) float f32x4;

#define MFMA(a, b, c) __builtin_amdgcn_mfma_f32_16x16x32_bf16(a, b, c, 0, 0, 0)
#define MFMA16(a, b, c) __builtin_amdgcn_mfma_f32_16x16x16bf16_1k(a, b, c, 0, 0, 0)

__device__ __forceinline__ unsigned short f2bf(float f) {
    union { __hip_bfloat16 b; unsigned short u; } c;
    c.b = __float2bfloat16(f);
    return c.u;
}

// ---------------------------------------------------------------------------
// bucket_cvt_kernel: blocks 0..63 = bucket partition; blocks 64.. = convert
// all 3 X inputs + all 3 W matrices to bf16 (independent work, one launch).
// ---------------------------------------------------------------------------
__global__ __launch_bounds__(256) void bucket_cvt_kernel(
    const int* __restrict__ hq, const int* __restrict__ hk,
    int* __restrict__ qorder, int* __restrict__ korder,
    int* __restrict__ qinv, int* __restrict__ kinv, int* __restrict__ cnts,
    const float* __restrict__ X0, const float* __restrict__ X1,
    const float* __restrict__ X2,
    const float* __restrict__ W0, const float* __restrict__ W1,
    const float* __restrict__ W2,
    unsigned short* __restrict__ xo0, unsigned short* __restrict__ xo1,
    unsigned short* __restrict__ xo2,
    unsigned short* __restrict__ wo0, unsigned short* __restrict__ wo1,
    unsigned short* __restrict__ wo2)
{
    __shared__ int cnt[257];
    const int t = threadIdx.x;
    if (blockIdx.x < 64) {
        const int blk = blockIdx.x;
        const int bh = blk >> 1;
        const int which = blk & 1;
        const int* src = (which ? hk : hq) + (size_t)bh * SEQ;
        int* dst = (which ? korder : qorder) + (size_t)bh * SEQ;
        int* ivd = (which ? kinv : qinv) + (size_t)bh * SEQ;

        int h[8]; int c = 0;
#pragma unroll
        for (int j = 0; j < 8; j++) { h[j] = src[t * 8 + j]; c += (h[j] == 0); }
        cnt[t] = c;
        __syncthreads();
        if (t == 0) {
            int run = 0;
            for (int i = 0; i < 256; i++) { int v = cnt[i]; cnt[i] = run; run += v; }
            cnt[256] = run;
        }
        __syncthreads();
        const int nz = cnt[256];
        int zpos = cnt[t];
        int opos = nz + t * 8 - cnt[t];
#pragma unroll
        for (int j = 0; j < 8; j++) {
            int idx = t * 8 + j;
            if (h[j] == 0) { dst[zpos] = idx; ivd[idx] = zpos; zpos++; }
            else           { dst[opos] = idx; ivd[idx] = opos; opos++; }
        }
        if (t == 0) cnts[which * 32 + bh] = nz;
        return;
    }

    // cvt section: g in [0, 1,966,080) groups of 8 elems
    const size_t g = (size_t)(blockIdx.x - 64) * 256 + t;
    const float* s; unsigned short* d; size_t off;
    if (g < 1572864) {
        int which = (int)(g / 524288);
        off = (g % 524288) * 8;
        s = which == 0 ? X0 : (which == 1 ? X1 : X2);
        d = which == 0 ? xo0 : (which == 1 ? xo1 : xo2);
    } else {
        size_t g2 = g - 1572864;
        int which = (int)(g2 / 131072);
        off = (g2 % 131072) * 8;
        s = which == 0 ? W0 : (which == 1 ? W1 : W2);
        d = which == 0 ? wo0 : (which == 1 ? wo1 : wo2);
    }
    f32x4 v0 = *(const f32x4*)(s + off);
    f32x4 v1 = *(const f32x4*)(s + off + 4);
    union { short8_t v; unsigned short u[8]; } o;
#pragma unroll
    for (int j = 0; j < 4; j++) {
        o.u[j]     = f2bf(v0[j]);
        o.u[4 + j] = f2bf(v1[j]);
    }
    *(short8_t*)(d + off) = o.v;
}

// ---------------------------------------------------------------------------
// bucket_kernel (fallback path) — identical logic, standalone.
// ---------------------------------------------------------------------------
__global__ __launch_bounds__(256) void bucket_kernel(
    const int* __restrict__ hq, const int* __restrict__ hk,
    int* __restrict__ qorder, int* __restrict__ korder,
    int* __restrict__ qinv, int* __restrict__ kinv, int* __restrict__ cnts)
{
    const int blk = blockIdx.x;
    const int bh = blk >> 1;
    const int which = blk & 1;
    const int* src = (which ? hk : hq) + (size_t)bh * SEQ;
    int* dst = (which ? korder : qorder) + (size_t)bh * SEQ;
    int* ivd = (which ? kinv : qinv) + (size_t)bh * SEQ;

    __shared__ int cnt[257];
    const int t = threadIdx.x;
    int h[8]; int c = 0;
#pragma unroll
    for (int j = 0; j < 8; j++) { h[j] = src[t * 8 + j]; c += (h[j] == 0); }
    cnt[t] = c;
    __syncthreads();
    if (t == 0) {
        int run = 0;
        for (int i = 0; i < 256; i++) { int v = cnt[i]; cnt[i] = run; run += v; }
        cnt[256] = run;
    }
    __syncthreads();
    const int nz = cnt[256];
    int zpos = cnt[t];
    int opos = nz + t * 8 - cnt[t];
#pragma unroll
    for (int j = 0; j < 8; j++) {
        int idx = t * 8 + j;
        if (h[j] == 0) { dst[zpos] = idx; ivd[idx] = zpos; zpos++; }
        else           { dst[opos] = idx; ivd[idx] = opos; opos++; }
    }
    if (t == 0) cnts[which * 32 + bh] = nz;
}

// ---------------------------------------------------------------------------
// cvt_xw (fallback path): X (4M f32) -> bf16, W (1M f32) -> bf16.
// ---------------------------------------------------------------------------
__global__ __launch_bounds__(256) void cvt_xw_kernel(
    const float* __restrict__ X, const float* __restrict__ W,
    unsigned short* __restrict__ Xb, unsigned short* __restrict__ Wb)
{
    const size_t t = (size_t)blockIdx.x * 256 + threadIdx.x;
    const float* src;
    unsigned short* dst;
    size_t i8;
    if (t < 524288) { src = X; dst = Xb; i8 = t * 8; }
    else            { src = W; dst = Wb; i8 = (t - 524288) * 8; }
    f32x4 v0 = *(const f32x4*)(src + i8);
    f32x4 v1 = *(const f32x4*)(src + i8 + 4);
    union { short8_t v; unsigned short u[8]; } o;
#pragma unroll
    for (int j = 0; j < 4; j++) {
        o.u[j]     = f2bf(v0[j]);
        o.u[4 + j] = f2bf(v1[j]);
    }
    *(short8_t*)(dst + i8) = o.v;
}

// ---------------------------------------------------------------------------
// proj_kernel (r15-proven): tile 128(A) x 64(B), BK=64, dbuf gld_lds +
// counted vmcnt(6). grp = grpBase + blockIdx.x/512; local = blockIdx.x & 511.
// grp 0: Q (row-scatter qinv); grp 1: K (row-scatter kinv); grp 2: V^T nat.
// ---------------------------------------------------------------------------
__global__ __launch_bounds__(256) void proj_kernel(
    const unsigned short* __restrict__ Xq, const unsigned short* __restrict__ Xk,
    const unsigned short* __restrict__ Xv,
    const unsigned short* __restrict__ Wq, const unsigned short* __restrict__ Wk,
    const unsigned short* __restrict__ Wv,
    const float* __restrict__ bq, const float* __restrict__ bk,
    const float* __restrict__ bv,
    const int* __restrict__ qinv, const int* __restrict__ kinv,
    unsigned short* __restrict__ pQ, unsigned short* __restrict__ pK,
    unsigned short* __restrict__ pVn, int grpBase)
{
    __shared__ unsigned short At[2][128 * 64];
    __shared__ unsigned short Bt[2][64 * 64];

    const int tid = threadIdx.x;
    const int lane = tid & 63;
    const int wv = tid >> 6;
    const int fr = lane & 15;
    const int fg = lane >> 4;
    const int srw = lane >> 3;
    const int su = lane & 7;

    const int grp = grpBase + (blockIdx.x >> 9);
    const int local = blockIdx.x & 511;
    const int xg = local & 7;               // XCD group
    const int j = local >> 3;               // 0..63
    const bool mode1 = (grp == 2);

    const unsigned short* Xb = grp == 0 ? Xq : (grp == 1 ? Xk : Xv);
    const unsigned short* Wb = grp == 0 ? Wq : (grp == 1 ? Wk : Wv);
    const float* bias = grp == 0 ? bq : (grp == 1 ? bk : bv);
    const int* inv = grp == 0 ? qinv : kinv;
    unsigned short* dst = grp == 0 ? pQ : (grp == 1 ? pK : pVn);

    const unsigned short* Ap; const unsigned short* Bp;
    int m0, n0;
    if (!mode1) {
        Ap = Xb; Bp = Wb;
        m0 = ((xg << 2) + (j >> 4)) * 128;
        n0 = (j & 15) * 64;
    } else {
        Ap = Wb; Bp = Xb;
        m0 = (j & 7) * 128;
        n0 = ((xg << 3) + (j >> 3)) * 64;
    }

    const unsigned short* aS[4]; const unsigned short* bS[2];
#pragma unroll
    for (int i = 0; i < 4; i++) {
        int r = wv * 32 + i * 8 + srw;
        aS[i] = Ap + (size_t)(m0 + r) * DMODEL + ((su ^ (r & 7)) << 3);
    }
#pragma unroll
    for (int i = 0; i < 2; i++) {
        int r = wv * 16 + i * 8 + srw;
        bS[i] = Bp + (size_t)(n0 + r) * DMODEL + ((su ^ (r & 7)) << 3);
    }

    f32x4 acc[2][4];
    const f32x4 fzero = {0.f, 0.f, 0.f, 0.f};
#pragma unroll
    for (int mf = 0; mf < 2; mf++)
#pragma unroll
        for (int nf = 0; nf < 4; nf++) acc[mf][nf] = fzero;

#define PSTAGE(K0, BI)                                                        \
    {                                                                         \
        _Pragma("unroll")                                                     \
        for (int i = 0; i < 4; i++)                                           \
            __builtin_amdgcn_global_load_lds(                                 \
                (const void*)(aS[i] + (K0)),                                  \
                (void*)&At[BI][(wv * 32 + i * 8) * 64], 16, 0, 0);            \
        _Pragma("unroll")                                                     \
        for (int i = 0; i < 2; i++)                                           \
            __builtin_amdgcn_global_load_lds(                                 \
                (const void*)(bS[i] + (K0)),                                  \
                (void*)&Bt[BI][(wv * 16 + i * 8) * 64], 16, 0, 0);            \
    }

    PSTAGE(0, 0);
    int cur = 0;

    for (int kk = 0; kk < 16; kk++) {
        if (kk < 15) {
            PSTAGE((kk + 1) * 64, cur ^ 1);
            asm volatile("s_waitcnt vmcnt(6)" ::: "memory");  // tile kk landed
        } else {
            asm volatile("s_waitcnt vmcnt(0)" ::: "memory");
        }
        __builtin_amdgcn_sched_barrier(0);
        __builtin_amdgcn_s_barrier();
        __builtin_amdgcn_sched_barrier(0);

        short8_t a[2][2], b[4][2];
#pragma unroll
        for (int mf = 0; mf < 2; mf++)
#pragma unroll
            for (int ks = 0; ks < 2; ks++) {
                int r = wv * 32 + mf * 16 + fr;
                int u = (ks * 4 + fg) ^ (fr & 7);
                a[mf][ks] = *(const short8_t*)&At[cur][r * 64 + u * 8];
            }
#pragma unroll
        for (int nf = 0; nf < 4; nf++)
#pragma unroll
            for (int ks = 0; ks < 2; ks++) {
                int r = nf * 16 + fr;
                int u = (ks * 4 + fg) ^ (fr & 7);
                b[nf][ks] = *(const short8_t*)&Bt[cur][r * 64 + u * 8];
            }
#pragma unroll
        for (int ks = 0; ks < 2; ks++)
#pragma unroll
            for (int mf = 0; mf < 2; mf++)
#pragma unroll
                for (int nf = 0; nf < 4; nf++)
                    acc[mf][nf] = MFMA(a[mf][ks], b[nf][ks], acc[mf][nf]);

        __builtin_amdgcn_sched_barrier(0);
        __builtin_amdgcn_s_barrier();      // all reads of buf[cur] done
        __builtin_amdgcn_sched_barrier(0);
        cur ^= 1;
    }
#undef PSTAGE

    if (!mode1) {
        const int hh = n0 >> 6;
#pragma unroll
        for (int mf = 0; mf < 2; mf++)
#pragma unroll
            for (int r = 0; r < 4; r++) {
                int gm = m0 + wv * 32 + mf * 16 + fg * 4 + r;   // b*2048+l
                int bb = gm >> 11;
                int bh = bb * NHEAD + hh;
                int pos = inv[(size_t)bh * SEQ + (gm & (SEQ - 1))];
                unsigned short* drow = dst + ((size_t)bh * SEQ + pos) * DK;
#pragma unroll
                for (int nf = 0; nf < 4; nf++) {
                    float v = acc[mf][nf][r] + bias[n0 + nf * 16 + fr];
                    drow[nf * 16 + fr] = f2bf(v);
                }
            }
    } else {
        const int bb = n0 >> 11;
#pragma unroll
        for (int mf = 0; mf < 2; mf++)
#pragma unroll
            for (int r = 0; r < 4; r++) {
                int od = m0 + wv * 32 + mf * 16 + fg * 4 + r;   // h*64+d
                int h = od >> 6;
                int bh = bb * NHEAD + h;
                float bvv = bias[od];
                unsigned short* drow =
                    dst + ((size_t)bh * DK + (od & 63)) * SEQ + (n0 & (SEQ - 1));
#pragma unroll
                for (int nf = 0; nf < 4; nf++) {
                    float v = acc[mf][nf][r] + bvv;
                    drow[nf * 16 + fr] = f2bf(v);
                }
            }
    }
}

// ---------------------------------------------------------------------------
// vperm: Vs[bh][d][pos] = Vn[bh][d][korder[bh][pos]]  (gather along keys)
// ---------------------------------------------------------------------------
__global__ __launch_bounds__(256) void vperm_kernel(
    const unsigned short* __restrict__ Vn, const int* __restrict__ korder,
    unsigned short* __restrict__ Vs)
{
    const int blk = blockIdx.x;       // 0..2047 = bh*64 + d
    const int bh = blk >> 6;
    const int d  = blk & 63;
    const int t = threadIdx.x;        // pos = t*8
    const int* kop = korder + (size_t)bh * SEQ + t * 8;
    const unsigned short* src = Vn + ((size_t)bh * DK + d) * SEQ;
    union { short8_t v; unsigned short u[8]; } o;
#pragma unroll
    for (int j = 0; j < 8; j++) o.u[j] = src[kop[j]];
    *(short8_t*)(Vs + ((size_t)bh * DK + d) * SEQ + t * 8) = o.v;
}

// ---------------------------------------------------------------------------
// LSH flash attention, V-FROM-GLOBAL: only K is LDS-staged (16KB dbuf);
// PV A-fragments read per-lane directly from sorted V^T in global (L1/L2-hot,
// issued at iteration top so QK+softmax hides the latency; the compiler's
// counted waitcnt lands before PV). Halves LDS traffic per block-tile
// (96KB -> 48KB) and removes the V bank conflicts. K staging: counted
// vmcnt(18)/(16) keeps V(i) + K(i+1) in flight across the barrier.
// Grid: 1056 = 8 XCD x (4 heads x 33 slots).
// ---------------------------------------------------------------------------
__global__ __launch_bounds__(256, 4) void lsh_attn_kernel(
    const unsigned short* __restrict__ Qs,
    const unsigned short* __restrict__ Ks, const unsigned short* __restrict__ Vst,
    const int* __restrict__ qorder, const int* __restrict__ cnts,
    float* __restrict__ out)
{
    __shared__ unsigned short KtL[2][64 * 64];

    const int tid = threadIdx.x;
    const int lane = tid & 63;
    const int wv = tid >> 6;
    const int fr = lane & 15;
    const int fg = lane >> 4;

    // XCD-grouped mapping: 1056 = 8 XCD x (4 heads x 33 slots)
    const int flat = blockIdx.x;
    const int xcd = flat & 7;
    const int s2 = flat >> 3;                 // 0..131
    const int bh = (xcd << 2) + (s2 / 33);    // b*16 + h
    const int slot = s2 % 33;

    const int nq0 = cnts[bh];
    const int nk0 = cnts[32 + bh];
    const int c0 = (nq0 + 63) >> 6;           // q-tiles covering bucket 0

    int B, qlo, qhi;
    if (slot < c0) {
        B = 0; qlo = slot << 6; qhi = min(qlo + 64, nq0);
    } else {
        B = 1; qlo = nq0 + ((slot - c0) << 6);
        if (qlo >= SEQ) return;               // block-uniform: safe w/ barriers
        qhi = min(qlo + 64, SEQ);
    }
    const int klo = B ? (nk0 >> 6) : 0;
    const int khi = B ? (SEQ >> 6) : ((nk0 + 63) >> 6);
    const int nt = khi - klo;

    const size_t base = (size_t)bh * SEQ * DK;
    const unsigned short* Kb = Ks + base;                    // [pos][d]
    const unsigned short* Vb = Vst + (size_t)bh * DK * SEQ;  // [d][pos]

    const int srw = lane >> 3;
    const int su = lane & 7;

    // Q fragments (B-operand of swapped QK: lane fr = q-row qlo + wv*16 + fr)
    short8_t q_hi[2];
    {
        const size_t ro = base + (size_t)(qlo + wv * 16 + fr) * DK;
        q_hi[0] = *(const short8_t*)(Qs + ro + fg * 8);
        q_hi[1] = *(const short8_t*)(Qs + ro + 32 + fg * 8);
    }

    const int swz = fr & 7;
    const int u0 = ((fg ^ swz) << 3);
    const int u1 = (((4 + fg) ^ swz) << 3);

    // V^T per-dt global row bases: lane reads V^T[dt*16+fr][k0 + kg*16 + fg*4]
    const unsigned short* vB[4];
#pragma unroll
    for (int dt = 0; dt < 4; dt++)
        vB[dt] = Vb + (size_t)(dt * 16 + fr) * SEQ + fg * 4;

    const float C2 = 0.18033688011112042f;    // 0.125 * log2(e)
    const float B2 = -14.426950408889634f;    // -10 * log2(e)

    const short4_t ones = {(short)0x3F80, (short)0x3F80, (short)0x3F80, (short)0x3F80};
    f32x4 acc_sum;
    f32x4 o_acc[4];
    const f32x4 fzero = {0.f, 0.f, 0.f, 0.f};
    acc_sum = fzero;
#pragma unroll
    for (int t = 0; t < 4; t++) o_acc[t] = fzero;

#define STAGE_K(T, BI)                                                        \
    {                                                                         \
        const int k0s = (T) << 6;                                             \
        _Pragma("unroll")                                                     \
        for (int i = 0; i < 2; i++) {                                         \
            const int r = wv * 16 + i * 8 + srw;                              \
            const int uo = ((su ^ (r & 7)) << 3);                             \
            __builtin_amdgcn_global_load_lds(                                 \
                (const void*)(Kb + (size_t)(k0s + r) * DK + uo),              \
                (void*)&KtL[BI][(wv * 16 + i * 8) * 64], 16, 0, 0);           \
        }                                                                     \
    }

    STAGE_K(klo, 0);
    int cur = 0;

    for (int i = 0; i < nt; i++) {
        const int k0 = (klo + i) << 6;

        // ---- issue V(i) global loads FIRST (latency hides under QK+softmax)
        short4_t vfr[4][4];
#pragma unroll
        for (int dt = 0; dt < 4; dt++)
#pragma unroll
            for (int kg = 0; kg < 4; kg++)
                vfr[dt][kg] = *(const short4_t*)(vB[dt] + k0 + kg * 16);

        // ---- K(i+1) staging; wait only K(i) (oldest 2), keep V+K(i+1) in flight
        if (i + 1 < nt) {
            STAGE_K(klo + i + 1, cur ^ 1);
            asm volatile("s_waitcnt vmcnt(18)" ::: "memory");  // K(i) landed
        } else {
            asm volatile("s_waitcnt vmcnt(16)" ::: "memory");  // K(i) landed
        }
        __builtin_amdgcn_sched_barrier(0);
        __builtin_amdgcn_s_barrier();         // K tile i visible to all waves
        __builtin_amdgcn_sched_barrier(0);

        // ---- S^T = K Q^T (8 MFMA; A = K rows, B = Q) ----
        f32x4 s[4];
#pragma unroll
        for (int kg = 0; kg < 4; kg++) {
            const int rr = (kg * 16 + fr) * 64;
            short8_t kc0 = *(const short8_t*)&KtL[cur][rr + u0];
            short8_t kc1 = *(const short8_t*)&KtL[cur][rr + u1];
            f32x4 a = fzero;
            a = MFMA(kc0, q_hi[0], a);
            a = MFMA(kc1, q_hi[1], a);
            s[kg] = a;
        }

        // ---- softmax: p = exp2(s*C2 + B2); boundary tile masks by position ----
        short4_t pk[4];
        const bool mixed = B ? (k0 < nk0) : (k0 + 64 > nk0);
        if (!mixed) {
#pragma unroll
            for (int kg = 0; kg < 4; kg++) {
                union { short4_t v; unsigned short u[4]; } P;
#pragma unroll
                for (int r = 0; r < 4; r++)
                    P.u[r] = f2bf(exp2f(fmaf(s[kg][r], C2, B2)));
                pk[kg] = P.v;
            }
        } else {
#pragma unroll
            for (int kg = 0; kg < 4; kg++) {
                union { short4_t v; unsigned short u[4]; } P;
#pragma unroll
                for (int r = 0; r < 4; r++) {
                    int cb = (k0 + kg * 16 + fg * 4 + r) >= nk0;
                    float basev = (cb == B) ? B2 : -1e9f;
                    P.u[r] = f2bf(exp2f(fmaf(s[kg][r], C2, basev)));
                }
                pk[kg] = P.v;
            }
        }

        // ---- psum via MFMA: acc_sum[.][q] += sum_k P^T[k][q] ----
#pragma unroll
        for (int kg = 0; kg < 4; kg++)
            acc_sum = MFMA16(ones, pk[kg], acc_sum);

        // ---- O^T += V^T P^T (compiler waits vfr's vmcnt here) ----
#pragma unroll
        for (int dt = 0; dt < 4; dt++) {
            f32x4 acc = o_acc[dt];
#pragma unroll
            for (int kg = 0; kg < 4; kg++)
                acc = MFMA16(vfr[dt][kg], pk[kg], acc);
            o_acc[dt] = acc;
        }

        __builtin_amdgcn_sched_barrier(0);
        __builtin_amdgcn_s_barrier();         // KtL[cur] fully consumed
        __builtin_amdgcn_sched_barrier(0);
        cur ^= 1;
    }
#undef STAGE_K

    // acc_sum rows are identical; element 0 already holds the full psum for q=fr
    const float psum = acc_sum[0];

    // ---- epilogue: row q=fr scatter via qorder; cols contiguous -> float4 ----
    const int b = bh >> 4, h = bh & 15;
    const int qpos = qlo + wv * 16 + fr;
    if (qpos < qhi) {
        const int origq = qorder[(size_t)bh * SEQ + qpos];
        const float inv = 1.0f / psum;
        float* orow = out + ((size_t)(b * SEQ + origq)) * DMODEL + h * DK + fg * 4;
#pragma unroll
        for (int dt = 0; dt < 4; dt++) {
            f32x4 v = o_acc[dt];
            v *= inv;
            *(f32x4*)(orow + dt * 16) = v;
        }
    }
}

// ---------------------------------------------------------------------------

extern "C" void kernel_launch(void* const* d_in, const int* in_sizes, int n_in,
                              void* d_out, int out_size, void* d_ws, size_t ws_size,
                              hipStream_t stream)
{
    const float* query = (const float*)d_in[0];
    const float* key   = (const float*)d_in[1];
    const float* value = (const float*)d_in[2];
    const int* hash_q  = (const int*)d_in[3];
    const int* hash_k  = (const int*)d_in[4];
    const float* Wq    = (const float*)d_in[5];
    const float* bq    = (const float*)d_in[6];
    const float* Wk    = (const float*)d_in[7];
    const float* bk    = (const float*)d_in[8];
    const float* Wv    = (const float*)d_in[9];
    const float* bv    = (const float*)d_in[10];
    float* out = (float*)d_out;

    const size_t plane = (size_t)BATCH * NHEAD * SEQ * DK;   // 4,194,304 elems
    const size_t wsz = (size_t)DMODEL * DMODEL;              // 1,048,576 elems

    // Fused path needs: 4 planes + 3 X slots + 3 W slots + int arrays.
    const size_t needFused =
        (4 * plane + 3 * plane + 3 * wsz) * sizeof(unsigned short) +
        (4 * 65536 + 64) * sizeof(int);

    if (ws_size >= needFused) {
        // ---------------- 4-launch fused path ----------------
        unsigned short* ws = (unsigned short*)d_ws;
        unsigned short* pQ  = ws;
        unsigned short* pK  = ws + plane;
        unsigned short* pVt = ws + 2 * plane;                 // sorted V^T
        unsigned short* pVn = ws + 3 * plane;                 // natural V^T
        unsigned short* xq  = ws + 4 * plane;
        unsigned short* xk  = xq + plane;
        unsigned short* xv  = xk + plane;
        unsigned short* wqb = xv + plane;
        unsigned short* wkb = wqb + wsz;
        unsigned short* wvb = wkb + wsz;
        int* ip = (int*)(wvb + wsz);
        int* qorder = ip;
        int* korder = ip + 65536;
        int* qinv   = ip + 131072;
        int* kinv   = ip + 196608;
        int* cnts   = ip + 262144;

        bucket_cvt_kernel<<<64 + 7680, 256, 0, stream>>>(
            hash_q, hash_k, qorder, korder, qinv, kinv, cnts,
            query, key, value, Wq, Wk, Wv,
            xq, xk, xv, wqb, wkb, wvb);

        proj_kernel<<<1536, 256, 0, stream>>>(
            xq, xk, xv, wqb, wkb, wvb, bq, bk, bv,
            qinv, kinv, pQ, pK, pVn, 0);

        vperm_kernel<<<2048, 256, 0, stream>>>(pVn, korder, pVt);

        lsh_attn_kernel<<<dim3(1056), 256, 0, stream>>>(pQ, pK, pVt,
                                                        qorder, cnts, out);
    } else {
        // ---------------- fallback 9-launch path ----------------
        unsigned short* ws = (unsigned short*)d_ws;
        unsigned short* pQ    = ws;
        unsigned short* pK    = ws + plane;
        unsigned short* pVt   = ws + 2 * plane;
        unsigned short* pVn   = ws + 3 * plane;
        unsigned short* Xslot = ws + 4 * plane;
        unsigned short* Wslot = ws + 5 * plane;
        int* ip = (int*)(ws + 5 * plane + wsz);
        int* qorder = ip;
        int* korder = ip + 65536;
        int* qinv   = ip + 131072;
        int* kinv   = ip + 196608;
        int* cnts   = ip + 262144;

        bucket_kernel<<<64, 256, 0, stream>>>(hash_q, hash_k, qorder, korder,
                                              qinv, kinv, cnts);

        const int cvtBlocks = (int)((plane + wsz) / 8 / 256);

        cvt_xw_kernel<<<cvtBlocks, 256, 0, stream>>>(query, Wq, Xslot, Wslot);
        proj_kernel<<<512, 256, 0, stream>>>(Xslot, Xslot, Xslot,
                                             Wslot, Wslot, Wslot, bq, bq, bq,
                                             qinv, qinv, pQ, pQ, pQ, 0);

        cvt_xw_kernel<<<cvtBlocks, 256, 0, stream>>>(key, Wk, Xslot, Wslot);
        proj_kernel<<<512, 256, 0, stream>>>(Xslot, Xslot, Xslot,
                                             Wslot, Wslot, Wslot, bk, bk, bk,
                                             kinv, kinv, pK, pK, pK, 1);

        cvt_xw_kernel<<<cvtBlocks, 256, 0, stream>>>(value, Wv, Xslot, Wslot);
        proj_kernel<<<512, 256, 0, stream>>>(Xslot, Xslot, Xslot,
                                             Wslot, Wslot, Wslot, bv, bv, bv,
                                             kinv, kinv, pVn, pVn, pVn, 2);

        vperm_kernel<<<2048, 256, 0, stream>>>(pVn, korder, pVt);

        lsh_attn_kernel<<<dim3(1056), 256, 0, stream>>>(pQ, pK, pVt,
                                                        qorder, cnts, out);
    }
}

// Round 19
// 105.970 us; speedup vs baseline: 2.0681x; 2.0681x over previous
//
#include <hip/hip_runtime.h>
#include <hip/hip_bf16.h>
#include <stdint.h>
#include <math.h>

#define NHEAD 16
#define DK 64
#define SEQ 2048
#define BATCH 2
#define DMODEL 1024

typedef __attribute__((ext_vector_type(8))) short short8_t;
typedef __attribute__((ext_vector_type(4))) short short4_t;
typedef __attribute__((ext_vector_type(4))) float f32x4;

#define MFMA(a, b, c) __builtin_amdgcn_mfma_f32_16x16x32_bf16(a, b, c, 0, 0, 0)
#define MFMA16(a, b, c) __builtin_amdgcn_mfma_f32_16x16x16bf16_1k(a, b, c, 0, 0, 0)

__device__ __forceinline__ unsigned short f2bf(float f) {
    union { __hip_bfloat16 b; unsigned short u; } c;
    c.b = __float2bfloat16(f);
    return c.u;
}

// ---------------------------------------------------------------------------
// bucket_cvt_kernel: blocks 0..63 = bucket partition; blocks 64.. = convert
// all 3 X inputs + all 3 W matrices to bf16 (independent work, one launch).
// ---------------------------------------------------------------------------
__global__ __launch_bounds__(256) void bucket_cvt_kernel(
    const int* __restrict__ hq, const int* __restrict__ hk,
    int* __restrict__ qorder, int* __restrict__ korder,
    int* __restrict__ qinv, int* __restrict__ kinv, int* __restrict__ cnts,
    const float* __restrict__ X0, const float* __restrict__ X1,
    const float* __restrict__ X2,
    const float* __restrict__ W0, const float* __restrict__ W1,
    const float* __restrict__ W2,
    unsigned short* __restrict__ xo0, unsigned short* __restrict__ xo1,
    unsigned short* __restrict__ xo2,
    unsigned short* __restrict__ wo0, unsigned short* __restrict__ wo1,
    unsigned short* __restrict__ wo2)
{
    __shared__ int cnt[257];
    const int t = threadIdx.x;
    if (blockIdx.x < 64) {
        const int blk = blockIdx.x;
        const int bh = blk >> 1;
        const int which = blk & 1;
        const int* src = (which ? hk : hq) + (size_t)bh * SEQ;
        int* dst = (which ? korder : qorder) + (size_t)bh * SEQ;
        int* ivd = (which ? kinv : qinv) + (size_t)bh * SEQ;

        int h[8]; int c = 0;
#pragma unroll
        for (int j = 0; j < 8; j++) { h[j] = src[t * 8 + j]; c += (h[j] == 0); }
        cnt[t] = c;
        __syncthreads();
        if (t == 0) {
            int run = 0;
            for (int i = 0; i < 256; i++) { int v = cnt[i]; cnt[i] = run; run += v; }
            cnt[256] = run;
        }
        __syncthreads();
        const int nz = cnt[256];
        int zpos = cnt[t];
        int opos = nz + t * 8 - cnt[t];
#pragma unroll
        for (int j = 0; j < 8; j++) {
            int idx = t * 8 + j;
            if (h[j] == 0) { dst[zpos] = idx; ivd[idx] = zpos; zpos++; }
            else           { dst[opos] = idx; ivd[idx] = opos; opos++; }
        }
        if (t == 0) cnts[which * 32 + bh] = nz;
        return;
    }

    // cvt section: g in [0, 1,966,080) groups of 8 elems
    const size_t g = (size_t)(blockIdx.x - 64) * 256 + t;
    const float* s; unsigned short* d; size_t off;
    if (g < 1572864) {
        int which = (int)(g / 524288);
        off = (g % 524288) * 8;
        s = which == 0 ? X0 : (which == 1 ? X1 : X2);
        d = which == 0 ? xo0 : (which == 1 ? xo1 : xo2);
    } else {
        size_t g2 = g - 1572864;
        int which = (int)(g2 / 131072);
        off = (g2 % 131072) * 8;
        s = which == 0 ? W0 : (which == 1 ? W1 : W2);
        d = which == 0 ? wo0 : (which == 1 ? wo1 : wo2);
    }
    f32x4 v0 = *(const f32x4*)(s + off);
    f32x4 v1 = *(const f32x4*)(s + off + 4);
    union { short8_t v; unsigned short u[8]; } o;
#pragma unroll
    for (int j = 0; j < 4; j++) {
        o.u[j]     = f2bf(v0[j]);
        o.u[4 + j] = f2bf(v1[j]);
    }
    *(short8_t*)(d + off) = o.v;
}

// ---------------------------------------------------------------------------
// bucket_kernel (fallback path) — identical logic, standalone.
// ---------------------------------------------------------------------------
__global__ __launch_bounds__(256) void bucket_kernel(
    const int* __restrict__ hq, const int* __restrict__ hk,
    int* __restrict__ qorder, int* __restrict__ korder,
    int* __restrict__ qinv, int* __restrict__ kinv, int* __restrict__ cnts)
{
    const int blk = blockIdx.x;
    const int bh = blk >> 1;
    const int which = blk & 1;
    const int* src = (which ? hk : hq) + (size_t)bh * SEQ;
    int* dst = (which ? korder : qorder) + (size_t)bh * SEQ;
    int* ivd = (which ? kinv : qinv) + (size_t)bh * SEQ;

    __shared__ int cnt[257];
    const int t = threadIdx.x;
    int h[8]; int c = 0;
#pragma unroll
    for (int j = 0; j < 8; j++) { h[j] = src[t * 8 + j]; c += (h[j] == 0); }
    cnt[t] = c;
    __syncthreads();
    if (t == 0) {
        int run = 0;
        for (int i = 0; i < 256; i++) { int v = cnt[i]; cnt[i] = run; run += v; }
        cnt[256] = run;
    }
    __syncthreads();
    const int nz = cnt[256];
    int zpos = cnt[t];
    int opos = nz + t * 8 - cnt[t];
#pragma unroll
    for (int j = 0; j < 8; j++) {
        int idx = t * 8 + j;
        if (h[j] == 0) { dst[zpos] = idx; ivd[idx] = zpos; zpos++; }
        else           { dst[opos] = idx; ivd[idx] = opos; opos++; }
    }
    if (t == 0) cnts[which * 32 + bh] = nz;
}

// ---------------------------------------------------------------------------
// cvt_xw (fallback path): X (4M f32) -> bf16, W (1M f32) -> bf16.
// ---------------------------------------------------------------------------
__global__ __launch_bounds__(256) void cvt_xw_kernel(
    const float* __restrict__ X, const float* __restrict__ W,
    unsigned short* __restrict__ Xb, unsigned short* __restrict__ Wb)
{
    const size_t t = (size_t)blockIdx.x * 256 + threadIdx.x;
    const float* src;
    unsigned short* dst;
    size_t i8;
    if (t < 524288) { src = X; dst = Xb; i8 = t * 8; }
    else            { src = W; dst = Wb; i8 = (t - 524288) * 8; }
    f32x4 v0 = *(const f32x4*)(src + i8);
    f32x4 v1 = *(const f32x4*)(src + i8 + 4);
    union { short8_t v; unsigned short u[8]; } o;
#pragma unroll
    for (int j = 0; j < 4; j++) {
        o.u[j]     = f2bf(v0[j]);
        o.u[4 + j] = f2bf(v1[j]);
    }
    *(short8_t*)(dst + i8) = o.v;
}

// ---------------------------------------------------------------------------
// proj_kernel (r11/r15-proven): tile 128(A) x 64(B), BK=64, dbuf gld_lds +
// counted vmcnt(6). grp = grpBase + blockIdx.x/512; local = blockIdx.x & 511.
// grp 0: Q (row-scatter qinv); grp 1: K (row-scatter kinv); grp 2: V^T nat.
// ---------------------------------------------------------------------------
__global__ __launch_bounds__(256) void proj_kernel(
    const unsigned short* __restrict__ Xq, const unsigned short* __restrict__ Xk,
    const unsigned short* __restrict__ Xv,
    const unsigned short* __restrict__ Wq, const unsigned short* __restrict__ Wk,
    const unsigned short* __restrict__ Wv,
    const float* __restrict__ bq, const float* __restrict__ bk,
    const float* __restrict__ bv,
    const int* __restrict__ qinv, const int* __restrict__ kinv,
    unsigned short* __restrict__ pQ, unsigned short* __restrict__ pK,
    unsigned short* __restrict__ pVn, int grpBase)
{
    __shared__ unsigned short At[2][128 * 64];
    __shared__ unsigned short Bt[2][64 * 64];

    const int tid = threadIdx.x;
    const int lane = tid & 63;
    const int wv = tid >> 6;
    const int fr = lane & 15;
    const int fg = lane >> 4;
    const int srw = lane >> 3;
    const int su = lane & 7;

    const int grp = grpBase + (blockIdx.x >> 9);
    const int local = blockIdx.x & 511;
    const int xg = local & 7;               // XCD group
    const int j = local >> 3;               // 0..63
    const bool mode1 = (grp == 2);

    const unsigned short* Xb = grp == 0 ? Xq : (grp == 1 ? Xk : Xv);
    const unsigned short* Wb = grp == 0 ? Wq : (grp == 1 ? Wk : Wv);
    const float* bias = grp == 0 ? bq : (grp == 1 ? bk : bv);
    const int* inv = grp == 0 ? qinv : kinv;
    unsigned short* dst = grp == 0 ? pQ : (grp == 1 ? pK : pVn);

    const unsigned short* Ap; const unsigned short* Bp;
    int m0, n0;
    if (!mode1) {
        Ap = Xb; Bp = Wb;
        m0 = ((xg << 2) + (j >> 4)) * 128;
        n0 = (j & 15) * 64;
    } else {
        Ap = Wb; Bp = Xb;
        m0 = (j & 7) * 128;
        n0 = ((xg << 3) + (j >> 3)) * 64;
    }

    const unsigned short* aS[4]; const unsigned short* bS[2];
#pragma unroll
    for (int i = 0; i < 4; i++) {
        int r = wv * 32 + i * 8 + srw;
        aS[i] = Ap + (size_t)(m0 + r) * DMODEL + ((su ^ (r & 7)) << 3);
    }
#pragma unroll
    for (int i = 0; i < 2; i++) {
        int r = wv * 16 + i * 8 + srw;
        bS[i] = Bp + (size_t)(n0 + r) * DMODEL + ((su ^ (r & 7)) << 3);
    }

    f32x4 acc[2][4];
    const f32x4 fzero = {0.f, 0.f, 0.f, 0.f};
#pragma unroll
    for (int mf = 0; mf < 2; mf++)
#pragma unroll
        for (int nf = 0; nf < 4; nf++) acc[mf][nf] = fzero;

#define PSTAGE(K0, BI)                                                        \
    {                                                                         \
        _Pragma("unroll")                                                     \
        for (int i = 0; i < 4; i++)                                           \
            __builtin_amdgcn_global_load_lds(                                 \
                (const void*)(aS[i] + (K0)),                                  \
                (void*)&At[BI][(wv * 32 + i * 8) * 64], 16, 0, 0);            \
        _Pragma("unroll")                                                     \
        for (int i = 0; i < 2; i++)                                           \
            __builtin_amdgcn_global_load_lds(                                 \
                (const void*)(bS[i] + (K0)),                                  \
                (void*)&Bt[BI][(wv * 16 + i * 8) * 64], 16, 0, 0);            \
    }

    PSTAGE(0, 0);
    int cur = 0;

    for (int kk = 0; kk < 16; kk++) {
        if (kk < 15) {
            PSTAGE((kk + 1) * 64, cur ^ 1);
            asm volatile("s_waitcnt vmcnt(6)" ::: "memory");  // tile kk landed
        } else {
            asm volatile("s_waitcnt vmcnt(0)" ::: "memory");
        }
        __builtin_amdgcn_sched_barrier(0);
        __builtin_amdgcn_s_barrier();
        __builtin_amdgcn_sched_barrier(0);

        short8_t a[2][2], b[4][2];
#pragma unroll
        for (int mf = 0; mf < 2; mf++)
#pragma unroll
            for (int ks = 0; ks < 2; ks++) {
                int r = wv * 32 + mf * 16 + fr;
                int u = (ks * 4 + fg) ^ (fr & 7);
                a[mf][ks] = *(const short8_t*)&At[cur][r * 64 + u * 8];
            }
#pragma unroll
        for (int nf = 0; nf < 4; nf++)
#pragma unroll
            for (int ks = 0; ks < 2; ks++) {
                int r = nf * 16 + fr;
                int u = (ks * 4 + fg) ^ (fr & 7);
                b[nf][ks] = *(const short8_t*)&Bt[cur][r * 64 + u * 8];
            }
#pragma unroll
        for (int ks = 0; ks < 2; ks++)
#pragma unroll
            for (int mf = 0; mf < 2; mf++)
#pragma unroll
                for (int nf = 0; nf < 4; nf++)
                    acc[mf][nf] = MFMA(a[mf][ks], b[nf][ks], acc[mf][nf]);

        __builtin_amdgcn_sched_barrier(0);
        __builtin_amdgcn_s_barrier();      // all reads of buf[cur] done
        __builtin_amdgcn_sched_barrier(0);
        cur ^= 1;
    }
#undef PSTAGE

    if (!mode1) {
        const int hh = n0 >> 6;
#pragma unroll
        for (int mf = 0; mf < 2; mf++)
#pragma unroll
            for (int r = 0; r < 4; r++) {
                int gm = m0 + wv * 32 + mf * 16 + fg * 4 + r;   // b*2048+l
                int bb = gm >> 11;
                int bh = bb * NHEAD + hh;
                int pos = inv[(size_t)bh * SEQ + (gm & (SEQ - 1))];
                unsigned short* drow = dst + ((size_t)bh * SEQ + pos) * DK;
#pragma unroll
                for (int nf = 0; nf < 4; nf++) {
                    float v = acc[mf][nf][r] + bias[n0 + nf * 16 + fr];
                    drow[nf * 16 + fr] = f2bf(v);
                }
            }
    } else {
        const int bb = n0 >> 11;
#pragma unroll
        for (int mf = 0; mf < 2; mf++)
#pragma unroll
            for (int r = 0; r < 4; r++) {
                int od = m0 + wv * 32 + mf * 16 + fg * 4 + r;   // h*64+d
                int h = od >> 6;
                int bh = bb * NHEAD + h;
                float bvv = bias[od];
                unsigned short* drow =
                    dst + ((size_t)bh * DK + (od & 63)) * SEQ + (n0 & (SEQ - 1));
#pragma unroll
                for (int nf = 0; nf < 4; nf++) {
                    float v = acc[mf][nf][r] + bvv;
                    drow[nf * 16 + fr] = f2bf(v);
                }
            }
    }
}

// ---------------------------------------------------------------------------
// vperm: Vs[bh][d][pos] = Vn[bh][d][korder[bh][pos]]  (gather along keys)
// ---------------------------------------------------------------------------
__global__ __launch_bounds__(256) void vperm_kernel(
    const unsigned short* __restrict__ Vn, const int* __restrict__ korder,
    unsigned short* __restrict__ Vs)
{
    const int blk = blockIdx.x;       // 0..2047 = bh*64 + d
    const int bh = blk >> 6;
    const int d  = blk & 63;
    const int t = threadIdx.x;        // pos = t*8
    const int* kop = korder + (size_t)bh * SEQ + t * 8;
    const unsigned short* src = Vn + ((size_t)bh * DK + d) * SEQ;
    union { short8_t v; unsigned short u[8]; } o;
#pragma unroll
    for (int j = 0; j < 8; j++) o.u[j] = src[kop[j]];
    *(short8_t*)(Vs + ((size_t)bh * DK + d) * SEQ + t * 8) = o.v;
}

// ---------------------------------------------------------------------------
// LSH flash attention (r12/r15-proven best: 57.2-57.7us): bucket-sorted,
// bucket-aligned 64-row q-slots, swapped QK^T, in-register PV (16x16x16),
// psum via MFMA, double-buffer + counted-vmcnt 2-phase, launch_bounds(256,4).
// ---------------------------------------------------------------------------
__global__ __launch_bounds__(256, 4) void lsh_attn_kernel(
    const unsigned short* __restrict__ Qs,
    const unsigned short* __restrict__ Ks, const unsigned short* __restrict__ Vst,
    const int* __restrict__ qorder, const int* __restrict__ cnts,
    float* __restrict__ out)
{
    __shared__ unsigned short KtL[2][64 * 64];
    __shared__ unsigned short VtL[2][64 * 64];

    const int tid = threadIdx.x;
    const int lane = tid & 63;
    const int wv = tid >> 6;
    const int fr = lane & 15;
    const int fg = lane >> 4;

    // XCD-grouped mapping: 1056 = 8 XCD x (4 heads x 33 slots)
    const int flat = blockIdx.x;
    const int xcd = flat & 7;
    const int s2 = flat >> 3;                 // 0..131
    const int bh = (xcd << 2) + (s2 / 33);    // b*16 + h
    const int slot = s2 % 33;

    const int nq0 = cnts[bh];
    const int nk0 = cnts[32 + bh];
    const int c0 = (nq0 + 63) >> 6;           // q-tiles covering bucket 0

    int B, qlo, qhi;
    if (slot < c0) {
        B = 0; qlo = slot << 6; qhi = min(qlo + 64, nq0);
    } else {
        B = 1; qlo = nq0 + ((slot - c0) << 6);
        if (qlo >= SEQ) return;               // block-uniform: safe w/ barriers
        qhi = min(qlo + 64, SEQ);
    }
    const int klo = B ? (nk0 >> 6) : 0;
    const int khi = B ? (SEQ >> 6) : ((nk0 + 63) >> 6);
    const int nt = khi - klo;

    const size_t base = (size_t)bh * SEQ * DK;
    const unsigned short* Kb = Ks + base;                    // [pos][d]
    const unsigned short* Vb = Vst + (size_t)bh * DK * SEQ;  // [d][pos]

    const int srw = lane >> 3;
    const int su = lane & 7;

    // Q fragments (B-operand of swapped QK: lane fr = q-row qlo + wv*16 + fr)
    short8_t q_hi[2];
    {
        const size_t ro = base + (size_t)(qlo + wv * 16 + fr) * DK;
        q_hi[0] = *(const short8_t*)(Qs + ro + fg * 8);
        q_hi[1] = *(const short8_t*)(Qs + ro + 32 + fg * 8);
    }

    const int swz = fr & 7;
    const int u0 = ((fg ^ swz) << 3);
    const int u1 = (((4 + fg) ^ swz) << 3);
    int vuoff[4];
#pragma unroll
    for (int kg = 0; kg < 4; kg++)
        vuoff[kg] = (((kg * 2 + (fg >> 1)) ^ swz) << 3) + ((fg & 1) << 2);

    const float C2 = 0.18033688011112042f;    // 0.125 * log2(e)
    const float B2 = -14.426950408889634f;    // -10 * log2(e)

    const short4_t ones = {(short)0x3F80, (short)0x3F80, (short)0x3F80, (short)0x3F80};
    f32x4 acc_sum;
    f32x4 o_acc[4];
    const f32x4 fzero = {0.f, 0.f, 0.f, 0.f};
    acc_sum = fzero;
#pragma unroll
    for (int t = 0; t < 4; t++) o_acc[t] = fzero;

#define STAGE(T, BI)                                                          \
    {                                                                         \
        const int k0s = (T) << 6;                                             \
        _Pragma("unroll")                                                     \
        for (int i = 0; i < 2; i++) {                                         \
            const int r = wv * 16 + i * 8 + srw;                              \
            const int uo = ((su ^ (r & 7)) << 3);                             \
            __builtin_amdgcn_global_load_lds(                                 \
                (const void*)(Kb + (size_t)(k0s + r) * DK + uo),              \
                (void*)&KtL[BI][(wv * 16 + i * 8) * 64], 16, 0, 0);           \
            __builtin_amdgcn_global_load_lds(                                 \
                (const void*)(Vb + (size_t)r * SEQ + k0s + uo),               \
                (void*)&VtL[BI][(wv * 16 + i * 8) * 64], 16, 0, 0);           \
        }                                                                     \
    }

    STAGE(klo, 0);
    int cur = 0;

    for (int i = 0; i < nt; i++) {
        if (i + 1 < nt) {
            STAGE(klo + i + 1, cur ^ 1);      // 4 more loads in flight
            asm volatile("s_waitcnt vmcnt(4)" ::: "memory");  // tile i landed
        } else {
            asm volatile("s_waitcnt vmcnt(0)" ::: "memory");
        }
        __builtin_amdgcn_sched_barrier(0);
        __builtin_amdgcn_s_barrier();         // tile i visible to all waves
        __builtin_amdgcn_sched_barrier(0);

        const int k0 = (klo + i) << 6;

        // ---- V fragments into regs early (independent of S) ----
        short4_t vfr[4][4];
#pragma unroll
        for (int dt = 0; dt < 4; dt++)
#pragma unroll
            for (int kg = 0; kg < 4; kg++)
                vfr[dt][kg] = *(const short4_t*)&VtL[cur][(dt * 16 + fr) * 64 + vuoff[kg]];

        // ---- S^T = K Q^T (8 MFMA; A = K rows, B = Q) ----
        f32x4 s[4];
#pragma unroll
        for (int kg = 0; kg < 4; kg++) {
            const int rr = (kg * 16 + fr) * 64;
            short8_t kc0 = *(const short8_t*)&KtL[cur][rr + u0];
            short8_t kc1 = *(const short8_t*)&KtL[cur][rr + u1];
            f32x4 a = fzero;
            a = MFMA(kc0, q_hi[0], a);
            a = MFMA(kc1, q_hi[1], a);
            s[kg] = a;
        }

        // ---- softmax: p = exp2(s*C2 + B2); boundary tile masks by position ----
        short4_t pk[4];
        const bool mixed = B ? (k0 < nk0) : (k0 + 64 > nk0);
        if (!mixed) {
#pragma unroll
            for (int kg = 0; kg < 4; kg++) {
                union { short4_t v; unsigned short u[4]; } P;
#pragma unroll
                for (int r = 0; r < 4; r++)
                    P.u[r] = f2bf(exp2f(fmaf(s[kg][r], C2, B2)));
                pk[kg] = P.v;
            }
        } else {
#pragma unroll
            for (int kg = 0; kg < 4; kg++) {
                union { short4_t v; unsigned short u[4]; } P;
#pragma unroll
                for (int r = 0; r < 4; r++) {
                    int cb = (k0 + kg * 16 + fg * 4 + r) >= nk0;
                    float basev = (cb == B) ? B2 : -1e9f;
                    P.u[r] = f2bf(exp2f(fmaf(s[kg][r], C2, basev)));
                }
                pk[kg] = P.v;
            }
        }

        // ---- psum via MFMA: acc_sum[.][q] += sum_k P^T[k][q] ----
#pragma unroll
        for (int kg = 0; kg < 4; kg++)
            acc_sum = MFMA16(ones, pk[kg], acc_sum);

        // ---- O^T += V^T P^T (in-register A and B) ----
#pragma unroll
        for (int dt = 0; dt < 4; dt++) {
            f32x4 acc = o_acc[dt];
#pragma unroll
            for (int kg = 0; kg < 4; kg++)
                acc = MFMA16(vfr[dt][kg], pk[kg], acc);
            o_acc[dt] = acc;
        }

        __builtin_amdgcn_sched_barrier(0);
        __builtin_amdgcn_s_barrier();         // buf[cur] fully consumed
        __builtin_amdgcn_sched_barrier(0);
        cur ^= 1;
    }
#undef STAGE

    // acc_sum rows are identical; element 0 already holds the full psum for q=fr
    const float psum = acc_sum[0];

    // ---- epilogue: row q=fr scatter via qorder; cols contiguous -> float4 ----
    const int b = bh >> 4, h = bh & 15;
    const int qpos = qlo + wv * 16 + fr;
    if (qpos < qhi) {
        const int origq = qorder[(size_t)bh * SEQ + qpos];
        const float inv = 1.0f / psum;
        float* orow = out + ((size_t)(b * SEQ + origq)) * DMODEL + h * DK + fg * 4;
#pragma unroll
        for (int dt = 0; dt < 4; dt++) {
            f32x4 v = o_acc[dt];
            v *= inv;
            *(f32x4*)(orow + dt * 16) = v;
        }
    }
}

// ---------------------------------------------------------------------------

extern "C" void kernel_launch(void* const* d_in, const int* in_sizes, int n_in,
                              void* d_out, int out_size, void* d_ws, size_t ws_size,
                              hipStream_t stream)
{
    const float* query = (const float*)d_in[0];
    const float* key   = (const float*)d_in[1];
    const float* value = (const float*)d_in[2];
    const int* hash_q  = (const int*)d_in[3];
    const int* hash_k  = (const int*)d_in[4];
    const float* Wq    = (const float*)d_in[5];
    const float* bq    = (const float*)d_in[6];
    const float* Wk    = (const float*)d_in[7];
    const float* bk    = (const float*)d_in[8];
    const float* Wv    = (const float*)d_in[9];
    const float* bv    = (const float*)d_in[10];
    float* out = (float*)d_out;

    const size_t plane = (size_t)BATCH * NHEAD * SEQ * DK;   // 4,194,304 elems
    const size_t wsz = (size_t)DMODEL * DMODEL;              // 1,048,576 elems

    // Fused path needs: 4 planes + 3 X slots + 3 W slots + int arrays.
    const size_t needFused =
        (4 * plane + 3 * plane + 3 * wsz) * sizeof(unsigned short) +
        (4 * 65536 + 64) * sizeof(int);

    if (ws_size >= needFused) {
        // ---------------- 4-launch fused path ----------------
        unsigned short* ws = (unsigned short*)d_ws;
        unsigned short* pQ  = ws;
        unsigned short* pK  = ws + plane;
        unsigned short* pVt = ws + 2 * plane;                 // sorted V^T
        unsigned short* pVn = ws + 3 * plane;                 // natural V^T
        unsigned short* xq  = ws + 4 * plane;
        unsigned short* xk  = xq + plane;
        unsigned short* xv  = xk + plane;
        unsigned short* wqb = xv + plane;
        unsigned short* wkb = wqb + wsz;
        unsigned short* wvb = wkb + wsz;
        int* ip = (int*)(wvb + wsz);
        int* qorder = ip;
        int* korder = ip + 65536;
        int* qinv   = ip + 131072;
        int* kinv   = ip + 196608;
        int* cnts   = ip + 262144;

        bucket_cvt_kernel<<<64 + 7680, 256, 0, stream>>>(
            hash_q, hash_k, qorder, korder, qinv, kinv, cnts,
            query, key, value, Wq, Wk, Wv,
            xq, xk, xv, wqb, wkb, wvb);

        proj_kernel<<<1536, 256, 0, stream>>>(
            xq, xk, xv, wqb, wkb, wvb, bq, bk, bv,
            qinv, kinv, pQ, pK, pVn, 0);

        vperm_kernel<<<2048, 256, 0, stream>>>(pVn, korder, pVt);

        lsh_attn_kernel<<<dim3(1056), 256, 0, stream>>>(pQ, pK, pVt,
                                                        qorder, cnts, out);
    } else {
        // ---------------- fallback 9-launch path ----------------
        unsigned short* ws = (unsigned short*)d_ws;
        unsigned short* pQ    = ws;
        unsigned short* pK    = ws + plane;
        unsigned short* pVt   = ws + 2 * plane;
        unsigned short* pVn   = ws + 3 * plane;
        unsigned short* Xslot = ws + 4 * plane;
        unsigned short* Wslot = ws + 5 * plane;
        int* ip = (int*)(ws + 5 * plane + wsz);
        int* qorder = ip;
        int* korder = ip + 65536;
        int* qinv   = ip + 131072;
        int* kinv   = ip + 196608;
        int* cnts   = ip + 262144;

        bucket_kernel<<<64, 256, 0, stream>>>(hash_q, hash_k, qorder, korder,
                                              qinv, kinv, cnts);

        const int cvtBlocks = (int)((plane + wsz) / 8 / 256);

        cvt_xw_kernel<<<cvtBlocks, 256, 0, stream>>>(query, Wq, Xslot, Wslot);
        proj_kernel<<<512, 256, 0, stream>>>(Xslot, Xslot, Xslot,
                                             Wslot, Wslot, Wslot, bq, bq, bq,
                                             qinv, qinv, pQ, pQ, pQ, 0);

        cvt_xw_kernel<<<cvtBlocks, 256, 0, stream>>>(key, Wk, Xslot, Wslot);
        proj_kernel<<<512, 256, 0, stream>>>(Xslot, Xslot, Xslot,
                                             Wslot, Wslot, Wslot, bk, bk, bk,
                                             kinv, kinv, pK, pK, pK, 1);

        cvt_xw_kernel<<<cvtBlocks, 256, 0, stream>>>(value, Wv, Xslot, Wslot);
        proj_kernel<<<512, 256, 0, stream>>>(Xslot, Xslot, Xslot,
                                             Wslot, Wslot, Wslot, bv, bv, bv,
                                             kinv, kinv, pVn, pVn, pVn, 2);

        vperm_kernel<<<2048, 256, 0, stream>>>(pVn, korder, pVt);

        lsh_attn_kernel<<<dim3(1056), 256, 0, stream>>>(pQ, pK, pVt,
                                                        qorder, cnts, out);
    }
}

// Round 20
// 103.856 us; speedup vs baseline: 2.1102x; 1.0204x over previous
//
#include <hip/hip_runtime.h>
#include <hip/hip_bf16.h>
#include <stdint.h>
#include <math.h>

#define NHEAD 16
#define DK 64
#define SEQ 2048
#define BATCH 2
#define DMODEL 1024

typedef __attribute__((ext_vector_type(8))) short short8_t;
typedef __attribute__((ext_vector_type(4))) short short4_t;
typedef __attribute__((ext_vector_type(4))) float f32x4;

#define MFMA(a, b, c) __builtin_amdgcn_mfma_f32_16x16x32_bf16(a, b, c, 0, 0, 0)
#define MFMA16(a, b, c) __builtin_amdgcn_mfma_f32_16x16x16bf16_1k(a, b, c, 0, 0, 0)

__device__ __forceinline__ unsigned short f2bf(float f) {
    union { __hip_bfloat16 b; unsigned short u; } c;
    c.b = __float2bfloat16(f);
    return c.u;
}

// ---------------------------------------------------------------------------
// bucket_cvt_kernel: blocks 0..63 = bucket partition; blocks 64.. = convert
// all 3 X inputs + all 3 W matrices to bf16 (independent work, one launch).
// ---------------------------------------------------------------------------
__global__ __launch_bounds__(256) void bucket_cvt_kernel(
    const int* __restrict__ hq, const int* __restrict__ hk,
    int* __restrict__ qorder, int* __restrict__ korder,
    int* __restrict__ qinv, int* __restrict__ kinv, int* __restrict__ cnts,
    const float* __restrict__ X0, const float* __restrict__ X1,
    const float* __restrict__ X2,
    const float* __restrict__ W0, const float* __restrict__ W1,
    const float* __restrict__ W2,
    unsigned short* __restrict__ xo0, unsigned short* __restrict__ xo1,
    unsigned short* __restrict__ xo2,
    unsigned short* __restrict__ wo0, unsigned short* __restrict__ wo1,
    unsigned short* __restrict__ wo2)
{
    __shared__ int cnt[257];
    const int t = threadIdx.x;
    if (blockIdx.x < 64) {
        const int blk = blockIdx.x;
        const int bh = blk >> 1;
        const int which = blk & 1;
        const int* src = (which ? hk : hq) + (size_t)bh * SEQ;
        int* dst = (which ? korder : qorder) + (size_t)bh * SEQ;
        int* ivd = (which ? kinv : qinv) + (size_t)bh * SEQ;

        int h[8]; int c = 0;
#pragma unroll
        for (int j = 0; j < 8; j++) { h[j] = src[t * 8 + j]; c += (h[j] == 0); }
        cnt[t] = c;
        __syncthreads();
        if (t == 0) {
            int run = 0;
            for (int i = 0; i < 256; i++) { int v = cnt[i]; cnt[i] = run; run += v; }
            cnt[256] = run;
        }
        __syncthreads();
        const int nz = cnt[256];
        int zpos = cnt[t];
        int opos = nz + t * 8 - cnt[t];
#pragma unroll
        for (int j = 0; j < 8; j++) {
            int idx = t * 8 + j;
            if (h[j] == 0) { dst[zpos] = idx; ivd[idx] = zpos; zpos++; }
            else           { dst[opos] = idx; ivd[idx] = opos; opos++; }
        }
        if (t == 0) cnts[which * 32 + bh] = nz;
        return;
    }

    // cvt section: g in [0, 1,966,080) groups of 8 elems
    const size_t g = (size_t)(blockIdx.x - 64) * 256 + t;
    const float* s; unsigned short* d; size_t off;
    if (g < 1572864) {
        int which = (int)(g / 524288);
        off = (g % 524288) * 8;
        s = which == 0 ? X0 : (which == 1 ? X1 : X2);
        d = which == 0 ? xo0 : (which == 1 ? xo1 : xo2);
    } else {
        size_t g2 = g - 1572864;
        int which = (int)(g2 / 131072);
        off = (g2 % 131072) * 8;
        s = which == 0 ? W0 : (which == 1 ? W1 : W2);
        d = which == 0 ? wo0 : (which == 1 ? wo1 : wo2);
    }
    f32x4 v0 = *(const f32x4*)(s + off);
    f32x4 v1 = *(const f32x4*)(s + off + 4);
    union { short8_t v; unsigned short u[8]; } o;
#pragma unroll
    for (int j = 0; j < 4; j++) {
        o.u[j]     = f2bf(v0[j]);
        o.u[4 + j] = f2bf(v1[j]);
    }
    *(short8_t*)(d + off) = o.v;
}

// ---------------------------------------------------------------------------
// bucket_kernel (fallback path) — identical logic, standalone.
// ---------------------------------------------------------------------------
__global__ __launch_bounds__(256) void bucket_kernel(
    const int* __restrict__ hq, const int* __restrict__ hk,
    int* __restrict__ qorder, int* __restrict__ korder,
    int* __restrict__ qinv, int* __restrict__ kinv, int* __restrict__ cnts)
{
    const int blk = blockIdx.x;
    const int bh = blk >> 1;
    const int which = blk & 1;
    const int* src = (which ? hk : hq) + (size_t)bh * SEQ;
    int* dst = (which ? korder : qorder) + (size_t)bh * SEQ;
    int* ivd = (which ? kinv : qinv) + (size_t)bh * SEQ;

    __shared__ int cnt[257];
    const int t = threadIdx.x;
    int h[8]; int c = 0;
#pragma unroll
    for (int j = 0; j < 8; j++) { h[j] = src[t * 8 + j]; c += (h[j] == 0); }
    cnt[t] = c;
    __syncthreads();
    if (t == 0) {
        int run = 0;
        for (int i = 0; i < 256; i++) { int v = cnt[i]; cnt[i] = run; run += v; }
        cnt[256] = run;
    }
    __syncthreads();
    const int nz = cnt[256];
    int zpos = cnt[t];
    int opos = nz + t * 8 - cnt[t];
#pragma unroll
    for (int j = 0; j < 8; j++) {
        int idx = t * 8 + j;
        if (h[j] == 0) { dst[zpos] = idx; ivd[idx] = zpos; zpos++; }
        else           { dst[opos] = idx; ivd[idx] = opos; opos++; }
    }
    if (t == 0) cnts[which * 32 + bh] = nz;
}

// ---------------------------------------------------------------------------
// cvt_xw (fallback path): X (4M f32) -> bf16, W (1M f32) -> bf16.
// ---------------------------------------------------------------------------
__global__ __launch_bounds__(256) void cvt_xw_kernel(
    const float* __restrict__ X, const float* __restrict__ W,
    unsigned short* __restrict__ Xb, unsigned short* __restrict__ Wb)
{
    const size_t t = (size_t)blockIdx.x * 256 + threadIdx.x;
    const float* src;
    unsigned short* dst;
    size_t i8;
    if (t < 524288) { src = X; dst = Xb; i8 = t * 8; }
    else            { src = W; dst = Wb; i8 = (t - 524288) * 8; }
    f32x4 v0 = *(const f32x4*)(src + i8);
    f32x4 v1 = *(const f32x4*)(src + i8 + 4);
    union { short8_t v; unsigned short u[8]; } o;
#pragma unroll
    for (int j = 0; j < 4; j++) {
        o.u[j]     = f2bf(v0[j]);
        o.u[4 + j] = f2bf(v1[j]);
    }
    *(short8_t*)(dst + i8) = o.v;
}

// ---------------------------------------------------------------------------
// proj_kernel (r11/r15-proven): tile 128(A) x 64(B), BK=64, dbuf gld_lds +
// counted vmcnt(6). grp = grpBase + blockIdx.x/512; local = blockIdx.x & 511.
// grp 0: Q (row-scatter qinv); grp 1: K (row-scatter kinv); grp 2: V^T nat.
// ---------------------------------------------------------------------------
__global__ __launch_bounds__(256) void proj_kernel(
    const unsigned short* __restrict__ Xq, const unsigned short* __restrict__ Xk,
    const unsigned short* __restrict__ Xv,
    const unsigned short* __restrict__ Wq, const unsigned short* __restrict__ Wk,
    const unsigned short* __restrict__ Wv,
    const float* __restrict__ bq, const float* __restrict__ bk,
    const float* __restrict__ bv,
    const int* __restrict__ qinv, const int* __restrict__ kinv,
    unsigned short* __restrict__ pQ, unsigned short* __restrict__ pK,
    unsigned short* __restrict__ pVn, int grpBase)
{
    __shared__ unsigned short At[2][128 * 64];
    __shared__ unsigned short Bt[2][64 * 64];

    const int tid = threadIdx.x;
    const int lane = tid & 63;
    const int wv = tid >> 6;
    const int fr = lane & 15;
    const int fg = lane >> 4;
    const int srw = lane >> 3;
    const int su = lane & 7;

    const int grp = grpBase + (blockIdx.x >> 9);
    const int local = blockIdx.x & 511;
    const int xg = local & 7;               // XCD group
    const int j = local >> 3;               // 0..63
    const bool mode1 = (grp == 2);

    const unsigned short* Xb = grp == 0 ? Xq : (grp == 1 ? Xk : Xv);
    const unsigned short* Wb = grp == 0 ? Wq : (grp == 1 ? Wk : Wv);
    const float* bias = grp == 0 ? bq : (grp == 1 ? bk : bv);
    const int* inv = grp == 0 ? qinv : kinv;
    unsigned short* dst = grp == 0 ? pQ : (grp == 1 ? pK : pVn);

    const unsigned short* Ap; const unsigned short* Bp;
    int m0, n0;
    if (!mode1) {
        Ap = Xb; Bp = Wb;
        m0 = ((xg << 2) + (j >> 4)) * 128;
        n0 = (j & 15) * 64;
    } else {
        Ap = Wb; Bp = Xb;
        m0 = (j & 7) * 128;
        n0 = ((xg << 3) + (j >> 3)) * 64;
    }

    const unsigned short* aS[4]; const unsigned short* bS[2];
#pragma unroll
    for (int i = 0; i < 4; i++) {
        int r = wv * 32 + i * 8 + srw;
        aS[i] = Ap + (size_t)(m0 + r) * DMODEL + ((su ^ (r & 7)) << 3);
    }
#pragma unroll
    for (int i = 0; i < 2; i++) {
        int r = wv * 16 + i * 8 + srw;
        bS[i] = Bp + (size_t)(n0 + r) * DMODEL + ((su ^ (r & 7)) << 3);
    }

    f32x4 acc[2][4];
    const f32x4 fzero = {0.f, 0.f, 0.f, 0.f};
#pragma unroll
    for (int mf = 0; mf < 2; mf++)
#pragma unroll
        for (int nf = 0; nf < 4; nf++) acc[mf][nf] = fzero;

#define PSTAGE(K0, BI)                                                        \
    {                                                                         \
        _Pragma("unroll")                                                     \
        for (int i = 0; i < 4; i++)                                           \
            __builtin_amdgcn_global_load_lds(                                 \
                (const void*)(aS[i] + (K0)),                                  \
                (void*)&At[BI][(wv * 32 + i * 8) * 64], 16, 0, 0);            \
        _Pragma("unroll")                                                     \
        for (int i = 0; i < 2; i++)                                           \
            __builtin_amdgcn_global_load_lds(                                 \
                (const void*)(bS[i] + (K0)),                                  \
                (void*)&Bt[BI][(wv * 16 + i * 8) * 64], 16, 0, 0);            \
    }

    PSTAGE(0, 0);
    int cur = 0;

    for (int kk = 0; kk < 16; kk++) {
        if (kk < 15) {
            PSTAGE((kk + 1) * 64, cur ^ 1);
            asm volatile("s_waitcnt vmcnt(6)" ::: "memory");  // tile kk landed
        } else {
            asm volatile("s_waitcnt vmcnt(0)" ::: "memory");
        }
        __builtin_amdgcn_sched_barrier(0);
        __builtin_amdgcn_s_barrier();
        __builtin_amdgcn_sched_barrier(0);

        short8_t a[2][2], b[4][2];
#pragma unroll
        for (int mf = 0; mf < 2; mf++)
#pragma unroll
            for (int ks = 0; ks < 2; ks++) {
                int r = wv * 32 + mf * 16 + fr;
                int u = (ks * 4 + fg) ^ (fr & 7);
                a[mf][ks] = *(const short8_t*)&At[cur][r * 64 + u * 8];
            }
#pragma unroll
        for (int nf = 0; nf < 4; nf++)
#pragma unroll
            for (int ks = 0; ks < 2; ks++) {
                int r = nf * 16 + fr;
                int u = (ks * 4 + fg) ^ (fr & 7);
                b[nf][ks] = *(const short8_t*)&Bt[cur][r * 64 + u * 8];
            }
#pragma unroll
        for (int ks = 0; ks < 2; ks++)
#pragma unroll
            for (int mf = 0; mf < 2; mf++)
#pragma unroll
                for (int nf = 0; nf < 4; nf++)
                    acc[mf][nf] = MFMA(a[mf][ks], b[nf][ks], acc[mf][nf]);

        __builtin_amdgcn_sched_barrier(0);
        __builtin_amdgcn_s_barrier();      // all reads of buf[cur] done
        __builtin_amdgcn_sched_barrier(0);
        cur ^= 1;
    }
#undef PSTAGE

    if (!mode1) {
        const int hh = n0 >> 6;
#pragma unroll
        for (int mf = 0; mf < 2; mf++)
#pragma unroll
            for (int r = 0; r < 4; r++) {
                int gm = m0 + wv * 32 + mf * 16 + fg * 4 + r;   // b*2048+l
                int bb = gm >> 11;
                int bh = bb * NHEAD + hh;
                int pos = inv[(size_t)bh * SEQ + (gm & (SEQ - 1))];
                unsigned short* drow = dst + ((size_t)bh * SEQ + pos) * DK;
#pragma unroll
                for (int nf = 0; nf < 4; nf++) {
                    float v = acc[mf][nf][r] + bias[n0 + nf * 16 + fr];
                    drow[nf * 16 + fr] = f2bf(v);
                }
            }
    } else {
        const int bb = n0 >> 11;
#pragma unroll
        for (int mf = 0; mf < 2; mf++)
#pragma unroll
            for (int r = 0; r < 4; r++) {
                int od = m0 + wv * 32 + mf * 16 + fg * 4 + r;   // h*64+d
                int h = od >> 6;
                int bh = bb * NHEAD + h;
                float bvv = bias[od];
                unsigned short* drow =
                    dst + ((size_t)bh * DK + (od & 63)) * SEQ + (n0 & (SEQ - 1));
#pragma unroll
                for (int nf = 0; nf < 4; nf++) {
                    float v = acc[mf][nf][r] + bvv;
                    drow[nf * 16 + fr] = f2bf(v);
                }
            }
    }
}

// ---------------------------------------------------------------------------
// vperm: Vs[bh][d][pos] = Vn[bh][d][korder[bh][pos]]  (gather along keys)
// ---------------------------------------------------------------------------
__global__ __launch_bounds__(256) void vperm_kernel(
    const unsigned short* __restrict__ Vn, const int* __restrict__ korder,
    unsigned short* __restrict__ Vs)
{
    const int blk = blockIdx.x;       // 0..2047 = bh*64 + d
    const int bh = blk >> 6;
    const int d  = blk & 63;
    const int t = threadIdx.x;        // pos = t*8
    const int* kop = korder + (size_t)bh * SEQ + t * 8;
    const unsigned short* src = Vn + ((size_t)bh * DK + d) * SEQ;
    union { short8_t v; unsigned short u[8]; } o;
#pragma unroll
    for (int j = 0; j < 8; j++) o.u[j] = src[kop[j]];
    *(short8_t*)(Vs + ((size_t)bh * DK + d) * SEQ + t * 8) = o.v;
}

// ---------------------------------------------------------------------------
// LSH flash attention, PAIRED-TILE staging: stage tiles {2i,2i+1} into the
// two 8KB buffer pairs, ONE vmcnt(0)+barrier, compute both, ONE barrier.
// Synchronization per 2 tiles: 2 barriers + 1 wait (was 4 + 2). LDS stays
// 32KB (5 blocks/CU capacity); stage latency is hidden by TLP (other
// resident blocks in compute phase), not intra-block prefetch.
// Bucket-sorted, bucket-aligned 64-row q-slots, swapped QK^T, in-register
// PV (16x16x16), psum via MFMA. Grid: 1056 = 8 XCD x (4 heads x 33 slots).
// ---------------------------------------------------------------------------
__global__ __launch_bounds__(256, 4) void lsh_attn_kernel(
    const unsigned short* __restrict__ Qs,
    const unsigned short* __restrict__ Ks, const unsigned short* __restrict__ Vst,
    const int* __restrict__ qorder, const int* __restrict__ cnts,
    float* __restrict__ out)
{
    __shared__ unsigned short KtL[2][64 * 64];
    __shared__ unsigned short VtL[2][64 * 64];

    const int tid = threadIdx.x;
    const int lane = tid & 63;
    const int wv = tid >> 6;
    const int fr = lane & 15;
    const int fg = lane >> 4;

    // XCD-grouped mapping: 1056 = 8 XCD x (4 heads x 33 slots)
    const int flat = blockIdx.x;
    const int xcd = flat & 7;
    const int s2 = flat >> 3;                 // 0..131
    const int bh = (xcd << 2) + (s2 / 33);    // b*16 + h
    const int slot = s2 % 33;

    const int nq0 = cnts[bh];
    const int nk0 = cnts[32 + bh];
    const int c0 = (nq0 + 63) >> 6;           // q-tiles covering bucket 0

    int B, qlo, qhi;
    if (slot < c0) {
        B = 0; qlo = slot << 6; qhi = min(qlo + 64, nq0);
    } else {
        B = 1; qlo = nq0 + ((slot - c0) << 6);
        if (qlo >= SEQ) return;               // block-uniform: safe w/ barriers
        qhi = min(qlo + 64, SEQ);
    }
    const int klo = B ? (nk0 >> 6) : 0;
    const int khi = B ? (SEQ >> 6) : ((nk0 + 63) >> 6);

    const size_t base = (size_t)bh * SEQ * DK;
    const unsigned short* Kb = Ks + base;                    // [pos][d]
    const unsigned short* Vb = Vst + (size_t)bh * DK * SEQ;  // [d][pos]

    const int srw = lane >> 3;
    const int su = lane & 7;

    // Q fragments (B-operand of swapped QK: lane fr = q-row qlo + wv*16 + fr)
    short8_t q_hi[2];
    {
        const size_t ro = base + (size_t)(qlo + wv * 16 + fr) * DK;
        q_hi[0] = *(const short8_t*)(Qs + ro + fg * 8);
        q_hi[1] = *(const short8_t*)(Qs + ro + 32 + fg * 8);
    }

    const int swz = fr & 7;
    const int u0 = ((fg ^ swz) << 3);
    const int u1 = (((4 + fg) ^ swz) << 3);
    int vuoff[4];
#pragma unroll
    for (int kg = 0; kg < 4; kg++)
        vuoff[kg] = (((kg * 2 + (fg >> 1)) ^ swz) << 3) + ((fg & 1) << 2);

    const float C2 = 0.18033688011112042f;    // 0.125 * log2(e)
    const float B2 = -14.426950408889634f;    // -10 * log2(e)

    const short4_t ones = {(short)0x3F80, (short)0x3F80, (short)0x3F80, (short)0x3F80};
    f32x4 acc_sum;
    f32x4 o_acc[4];
    const f32x4 fzero = {0.f, 0.f, 0.f, 0.f};
    acc_sum = fzero;
#pragma unroll
    for (int t = 0; t < 4; t++) o_acc[t] = fzero;

#define STAGE(T, BI)                                                          \
    {                                                                         \
        const int k0s = (T) << 6;                                             \
        _Pragma("unroll")                                                     \
        for (int i = 0; i < 2; i++) {                                         \
            const int r = wv * 16 + i * 8 + srw;                              \
            const int uo = ((su ^ (r & 7)) << 3);                             \
            __builtin_amdgcn_global_load_lds(                                 \
                (const void*)(Kb + (size_t)(k0s + r) * DK + uo),              \
                (void*)&KtL[BI][(wv * 16 + i * 8) * 64], 16, 0, 0);           \
            __builtin_amdgcn_global_load_lds(                                 \
                (const void*)(Vb + (size_t)r * SEQ + k0s + uo),               \
                (void*)&VtL[BI][(wv * 16 + i * 8) * 64], 16, 0, 0);           \
        }                                                                     \
    }

    for (int i0 = klo; i0 < khi; i0 += 2) {
        const int np = min(2, khi - i0);

        // ---- stage the pair (8 gld_lds per wave) ----
        STAGE(i0, 0);
        if (np == 2) STAGE(i0 + 1, 1);
        asm volatile("s_waitcnt vmcnt(0)" ::: "memory");
        __builtin_amdgcn_sched_barrier(0);
        __builtin_amdgcn_s_barrier();         // pair visible to all waves
        __builtin_amdgcn_sched_barrier(0);

        // ---- compute both tiles of the pair ----
        for (int p = 0; p < np; p++) {
            const int k0 = (i0 + p) << 6;

            // V fragments into regs early (independent of S)
            short4_t vfr[4][4];
#pragma unroll
            for (int dt = 0; dt < 4; dt++)
#pragma unroll
                for (int kg = 0; kg < 4; kg++)
                    vfr[dt][kg] = *(const short4_t*)&VtL[p][(dt * 16 + fr) * 64 + vuoff[kg]];

            // S^T = K Q^T (8 MFMA; A = K rows, B = Q)
            f32x4 s[4];
#pragma unroll
            for (int kg = 0; kg < 4; kg++) {
                const int rr = (kg * 16 + fr) * 64;
                short8_t kc0 = *(const short8_t*)&KtL[p][rr + u0];
                short8_t kc1 = *(const short8_t*)&KtL[p][rr + u1];
                f32x4 a = fzero;
                a = MFMA(kc0, q_hi[0], a);
                a = MFMA(kc1, q_hi[1], a);
                s[kg] = a;
            }

            // softmax: p = exp2(s*C2 + B2); boundary tile masks by position
            short4_t pk[4];
            const bool mixed = B ? (k0 < nk0) : (k0 + 64 > nk0);
            if (!mixed) {
#pragma unroll
                for (int kg = 0; kg < 4; kg++) {
                    union { short4_t v; unsigned short u[4]; } P;
#pragma unroll
                    for (int r = 0; r < 4; r++)
                        P.u[r] = f2bf(exp2f(fmaf(s[kg][r], C2, B2)));
                    pk[kg] = P.v;
                }
            } else {
#pragma unroll
                for (int kg = 0; kg < 4; kg++) {
                    union { short4_t v; unsigned short u[4]; } P;
#pragma unroll
                    for (int r = 0; r < 4; r++) {
                        int cb = (k0 + kg * 16 + fg * 4 + r) >= nk0;
                        float basev = (cb == B) ? B2 : -1e9f;
                        P.u[r] = f2bf(exp2f(fmaf(s[kg][r], C2, basev)));
                    }
                    pk[kg] = P.v;
                }
            }

            // psum via MFMA
#pragma unroll
            for (int kg = 0; kg < 4; kg++)
                acc_sum = MFMA16(ones, pk[kg], acc_sum);

            // O^T += V^T P^T (in-register A and B)
#pragma unroll
            for (int dt = 0; dt < 4; dt++) {
                f32x4 acc = o_acc[dt];
#pragma unroll
                for (int kg = 0; kg < 4; kg++)
                    acc = MFMA16(vfr[dt][kg], pk[kg], acc);
                o_acc[dt] = acc;
            }
        }

        __builtin_amdgcn_sched_barrier(0);
        __builtin_amdgcn_s_barrier();         // pair fully consumed
        __builtin_amdgcn_sched_barrier(0);
    }
#undef STAGE

    // acc_sum rows are identical; element 0 already holds the full psum for q=fr
    const float psum = acc_sum[0];

    // ---- epilogue: row q=fr scatter via qorder; cols contiguous -> float4 ----
    const int b = bh >> 4, h = bh & 15;
    const int qpos = qlo + wv * 16 + fr;
    if (qpos < qhi) {
        const int origq = qorder[(size_t)bh * SEQ + qpos];
        const float inv = 1.0f / psum;
        float* orow = out + ((size_t)(b * SEQ + origq)) * DMODEL + h * DK + fg * 4;
#pragma unroll
        for (int dt = 0; dt < 4; dt++) {
            f32x4 v = o_acc[dt];
            v *= inv;
            *(f32x4*)(orow + dt * 16) = v;
        }
    }
}

// ---------------------------------------------------------------------------

extern "C" void kernel_launch(void* const* d_in, const int* in_sizes, int n_in,
                              void* d_out, int out_size, void* d_ws, size_t ws_size,
                              hipStream_t stream)
{
    const float* query = (const float*)d_in[0];
    const float* key   = (const float*)d_in[1];
    const float* value = (const float*)d_in[2];
    const int* hash_q  = (const int*)d_in[3];
    const int* hash_k  = (const int*)d_in[4];
    const float* Wq    = (const float*)d_in[5];
    const float* bq    = (const float*)d_in[6];
    const float* Wk    = (const float*)d_in[7];
    const float* bk    = (const float*)d_in[8];
    const float* Wv    = (const float*)d_in[9];
    const float* bv    = (const float*)d_in[10];
    float* out = (float*)d_out;

    const size_t plane = (size_t)BATCH * NHEAD * SEQ * DK;   // 4,194,304 elems
    const size_t wsz = (size_t)DMODEL * DMODEL;              // 1,048,576 elems

    // Fused path needs: 4 planes + 3 X slots + 3 W slots + int arrays.
    const size_t needFused =
        (4 * plane + 3 * plane + 3 * wsz) * sizeof(unsigned short) +
        (4 * 65536 + 64) * sizeof(int);

    if (ws_size >= needFused) {
        // ---------------- 4-launch fused path ----------------
        unsigned short* ws = (unsigned short*)d_ws;
        unsigned short* pQ  = ws;
        unsigned short* pK  = ws + plane;
        unsigned short* pVt = ws + 2 * plane;                 // sorted V^T
        unsigned short* pVn = ws + 3 * plane;                 // natural V^T
        unsigned short* xq  = ws + 4 * plane;
        unsigned short* xk  = xq + plane;
        unsigned short* xv  = xk + plane;
        unsigned short* wqb = xv + plane;
        unsigned short* wkb = wqb + wsz;
        unsigned short* wvb = wkb + wsz;
        int* ip = (int*)(wvb + wsz);
        int* qorder = ip;
        int* korder = ip + 65536;
        int* qinv   = ip + 131072;
        int* kinv   = ip + 196608;
        int* cnts   = ip + 262144;

        bucket_cvt_kernel<<<64 + 7680, 256, 0, stream>>>(
            hash_q, hash_k, qorder, korder, qinv, kinv, cnts,
            query, key, value, Wq, Wk, Wv,
            xq, xk, xv, wqb, wkb, wvb);

        proj_kernel<<<1536, 256, 0, stream>>>(
            xq, xk, xv, wqb, wkb, wvb, bq, bk, bv,
            qinv, kinv, pQ, pK, pVn, 0);

        vperm_kernel<<<2048, 256, 0, stream>>>(pVn, korder, pVt);

        lsh_attn_kernel<<<dim3(1056), 256, 0, stream>>>(pQ, pK, pVt,
                                                        qorder, cnts, out);
    } else {
        // ---------------- fallback 9-launch path ----------------
        unsigned short* ws = (unsigned short*)d_ws;
        unsigned short* pQ    = ws;
        unsigned short* pK    = ws + plane;
        unsigned short* pVt   = ws + 2 * plane;
        unsigned short* pVn   = ws + 3 * plane;
        unsigned short* Xslot = ws + 4 * plane;
        unsigned short* Wslot = ws + 5 * plane;
        int* ip = (int*)(ws + 5 * plane + wsz);
        int* qorder = ip;
        int* korder = ip + 65536;
        int* qinv   = ip + 131072;
        int* kinv   = ip + 196608;
        int* cnts   = ip + 262144;

        bucket_kernel<<<64, 256, 0, stream>>>(hash_q, hash_k, qorder, korder,
                                              qinv, kinv, cnts);

        const int cvtBlocks = (int)((plane + wsz) / 8 / 256);

        cvt_xw_kernel<<<cvtBlocks, 256, 0, stream>>>(query, Wq, Xslot, Wslot);
        proj_kernel<<<512, 256, 0, stream>>>(Xslot, Xslot, Xslot,
                                             Wslot, Wslot, Wslot, bq, bq, bq,
                                             qinv, qinv, pQ, pQ, pQ, 0);

        cvt_xw_kernel<<<cvtBlocks, 256, 0, stream>>>(key, Wk, Xslot, Wslot);
        proj_kernel<<<512, 256, 0, stream>>>(Xslot, Xslot, Xslot,
                                             Wslot, Wslot, Wslot, bk, bk, bk,
                                             kinv, kinv, pK, pK, pK, 1);

        cvt_xw_kernel<<<cvtBlocks, 256, 0, stream>>>(value, Wv, Xslot, Wslot);
        proj_kernel<<<512, 256, 0, stream>>>(Xslot, Xslot, Xslot,
                                             Wslot, Wslot, Wslot, bv, bv, bv,
                                             kinv, kinv, pVn, pVn, pVn, 2);

        vperm_kernel<<<2048, 256, 0, stream>>>(pVn, korder, pVt);

        lsh_attn_kernel<<<dim3(1056), 256, 0, stream>>>(pQ, pK, pVt,
                                                        qorder, cnts, out);
    }
}